// Round 9
// baseline (532.099 us; speedup 1.0000x reference)
//
#include <hip/hip_runtime.h>
#include <hip/hip_bf16.h>

#define RELS 7
#define DIM 64
#define KTOT 512  // 7*64 + 64 (root)

typedef __attribute__((ext_vector_type(8))) short short8;
typedef __attribute__((ext_vector_type(4))) float floatx4;

__device__ inline unsigned short f2b(float f) {
  union { float f; unsigned u; } v; v.f = f;
  unsigned u = v.u + 0x7fffu + ((v.u >> 16) & 1u);  // round-nearest-even
  return (unsigned short)(u >> 16);
}
__device__ inline float b2f(unsigned short b) {
  union { unsigned u; float f; } v; v.u = ((unsigned)b) << 16;
  return v.f;
}

// x f32 -> bf16 (8 elems/thread)
__global__ void __launch_bounds__(256) k_xb(const float* __restrict__ x,
                                            unsigned short* __restrict__ xb, long n8) {
  long t = (long)blockIdx.x * 256 + threadIdx.x;
  if (t >= n8) return;
  const float4* p = reinterpret_cast<const float4*>(x + t * 8);
  float4 f0 = p[0], f1 = p[1];
  short8 o;
  o[0] = (short)f2b(f0.x); o[1] = (short)f2b(f0.y);
  o[2] = (short)f2b(f0.z); o[3] = (short)f2b(f0.w);
  o[4] = (short)f2b(f1.x); o[5] = (short)f2b(f1.y);
  o[6] = (short)f2b(f1.z); o[7] = (short)f2b(f1.w);
  *reinterpret_cast<short8*>(xb + t * 8) = o;
}

// [W;root] f32 -> bf16 in MFMA-fragment order (one-time, 64 KiB)
__global__ void __launch_bounds__(256) k_wb(const float* __restrict__ W,
                                            const float* __restrict__ root,
                                            unsigned short* __restrict__ Blg) {
  int g = blockIdx.x * 256 + threadIdx.x;  // 4096 groups
  if (g >= 4096) return;
  int kb = g >> 6, col = g & 63;
  short8 tmp;
#pragma unroll
  for (int j = 0; j < 8; ++j) {
    int k = kb * 8 + j;
    float w = (k < 448) ? W[k * 64 + col] : root[(k - 448) * 64 + col];
    tmp[j] = (short)f2b(w);
  }
  *reinterpret_cast<short8*>(&Blg[g * 8]) = tmp;
}

// histogram over (dst*8 + rel)
__global__ void __launch_bounds__(256) k_hist(const int* __restrict__ dst,
                                              const int* __restrict__ et,
                                              int* __restrict__ deg, int E) {
  int e = blockIdx.x * 256 + threadIdx.x;
  if (e < E) atomicAdd(&deg[(dst[e] << 3) + et[e]], 1);
}

// block-local exclusive scan over 1024 entries (256 thr x 4)
__global__ void __launch_bounds__(256) k_scan1(const int* __restrict__ deg,
                                               int* __restrict__ start,
                                               int* __restrict__ bsum, int n) {
  __shared__ int sm[256];
  int t = threadIdx.x;
  int base = blockIdx.x * 1024 + t * 4;
  int v0 = (base + 0 < n) ? deg[base + 0] : 0;
  int v1 = (base + 1 < n) ? deg[base + 1] : 0;
  int v2 = (base + 2 < n) ? deg[base + 2] : 0;
  int v3 = (base + 3 < n) ? deg[base + 3] : 0;
  int s = v0 + v1 + v2 + v3;
  sm[t] = s;
  __syncthreads();
  for (int off = 1; off < 256; off <<= 1) {
    int a = (t >= off) ? sm[t - off] : 0;
    __syncthreads();
    sm[t] += a;
    __syncthreads();
  }
  int excl = sm[t] - s;
  if (base + 0 < n) start[base + 0] = excl;
  excl += v0;
  if (base + 1 < n) start[base + 1] = excl;
  excl += v1;
  if (base + 2 < n) start[base + 2] = excl;
  excl += v2;
  if (base + 3 < n) start[base + 3] = excl;
  if (t == 255) bsum[blockIdx.x] = sm[255];
}

// single-block exclusive scan over up to 1024 block sums (in place)
__global__ void __launch_bounds__(256) k_scan2(int* bsum, int nb) {
  __shared__ int sm[256];
  int t = threadIdx.x;
  int base = t * 4;
  int v0 = (base + 0 < nb) ? bsum[base + 0] : 0;
  int v1 = (base + 1 < nb) ? bsum[base + 1] : 0;
  int v2 = (base + 2 < nb) ? bsum[base + 2] : 0;
  int v3 = (base + 3 < nb) ? bsum[base + 3] : 0;
  int s = v0 + v1 + v2 + v3;
  sm[t] = s;
  __syncthreads();
  for (int off = 1; off < 256; off <<= 1) {
    int a = (t >= off) ? sm[t - off] : 0;
    __syncthreads();
    sm[t] += a;
    __syncthreads();
  }
  int excl = sm[t] - s;
  if (base + 0 < nb) bsum[base + 0] = excl;
  excl += v0;
  if (base + 1 < nb) bsum[base + 1] = excl;
  excl += v1;
  if (base + 2 < nb) bsum[base + 2] = excl;
  excl += v2;
  if (base + 3 < nb) bsum[base + 3] = excl;
}

__global__ void __launch_bounds__(256) k_scan3(int* __restrict__ start,
                                               int* __restrict__ cursor,
                                               const int* __restrict__ bsum,
                                               int n, int E) {
  int i = blockIdx.x * 256 + threadIdx.x;
  if (i < n) {
    int v = start[i] + bsum[i >> 10];
    start[i] = v;
    cursor[i] = v;
  } else if (i == n) {
    start[n] = E;
  }
}

// esrc word: src | rel<<17   (src < 2^17, rel < 7)
__global__ void __launch_bounds__(256) k_bucket(const int* __restrict__ ei,
                                                const int* __restrict__ et,
                                                int* __restrict__ cursor,
                                                int* __restrict__ esrc, int E) {
  int e = blockIdx.x * 256 + threadIdx.x;
  if (e >= E) return;
  int s = ei[e], d = ei[E + e], r = et[e];
  int pos = atomicAdd(&cursor[(d << 3) + r], 1);
  esrc[pos] = s | (r << 17);
}

// ---------------- fused aggregation + GEMM ----------------
// Block = 64 nodes, 4 waves; wave wv aggregates nodes [g0, g0+16) into its own
// LDS A quadrant (bf16, MFMA-fragment order, XOR-swizzled), then runs the
// K=512 MFMA loop on those same 16 rows. B read from global (L2-hot).
__global__ void __launch_bounds__(256) k_fused(
    const int* __restrict__ start, const int* __restrict__ esrc,
    const unsigned short* __restrict__ xb, const unsigned short* __restrict__ Blg,
    const float* __restrict__ bias, float* __restrict__ out, int N, int NS)
{
  __shared__ unsigned short A[64 * KTOT];  // 64 KiB
  const int tid = threadIdx.x;
  const int lane = tid & 63;
  const int wv = tid >> 6;

  // ---- phase 1: aggregate 16 nodes ----
  const int g0 = blockIdx.x * 64 + (wv << 4);
  const int sbase = g0 << 3;
  int i0 = sbase + lane;      if (i0 > NS) i0 = NS;
  int i1 = sbase + 64 + lane; if (i1 > NS) i1 = NS;
  const int sv0 = start[i0];
  const int sv1 = start[i1];

  for (int n = 0; n < 16; ++n) {
    const int bidx = n << 3;
    // boundaries via shfl (index <= 127 always; r=7 bucket is empty)
    int a0 = (bidx < 64) ? __shfl(sv0, bidx, 64) : __shfl(sv1, bidx - 64, 64);
    int i7 = bidx + 7;
    int aE = (i7 < 64) ? __shfl(sv0, i7, 64) : __shfl(sv1, i7 - 64, 64);

    float acc0 = 0, acc1 = 0, acc2 = 0, acc3 = 0, acc4 = 0, acc5 = 0, acc6 = 0;

    for (int base = a0; base < aE; base += 64) {
      int idx = base + lane;
      int ew = (idx < aE) ? esrc[idx] : 0;
      int m = aE - base; if (m > 64) m = 64;
      for (int j0 = 0; j0 < m; j0 += 8) {
        int jm = m - j0; if (jm > 8) jm = 8;
        float g[8]; int rl[8];
#pragma unroll
        for (int j = 0; j < 8; ++j) {
          if (j < jm) {
            int w = __shfl(ew, j0 + j, 64);
            g[j] = b2f(xb[((long)(w & 0x1FFFF) << 6) + lane]);
            rl[j] = (w >> 17) & 7;
          }
        }
#pragma unroll
        for (int j = 0; j < 8; ++j) {
          if (j < jm) {
            int r = __builtin_amdgcn_readfirstlane(rl[j]);
            switch (r) {
              case 0: acc0 += g[j]; break;
              case 1: acc1 += g[j]; break;
              case 2: acc2 += g[j]; break;
              case 3: acc3 += g[j]; break;
              case 4: acc4 += g[j]; break;
              case 5: acc5 += g[j]; break;
              default: acc6 += g[j]; break;
            }
          }
        }
      }
    }

    // means -> LDS A row (bf16), swizzled: byte ^= (row&7)<<4
    const int row = (wv << 4) + n;
    const unsigned rbase = ((unsigned)row) << 10;
    const unsigned sw = ((unsigned)(row & 7)) << 4;
#pragma unroll
    for (int r = 0; r < RELS; ++r) {
      int ia = bidx + r, ib = bidx + r + 1;
      int s0 = (ia < 64) ? __shfl(sv0, ia, 64) : __shfl(sv1, ia - 64, 64);
      int s1 = (ib < 64) ? __shfl(sv0, ib, 64) : __shfl(sv1, ib - 64, 64);
      float a = (r == 0) ? acc0 : (r == 1) ? acc1 : (r == 2) ? acc2 :
                (r == 3) ? acc3 : (r == 4) ? acc4 : (r == 5) ? acc5 : acc6;
      float inv = __builtin_amdgcn_rcpf(fmaxf((float)(s1 - s0), 1.0f));
      unsigned byte = (rbase + ((unsigned)((r << 6) + lane) << 1)) ^ sw;
      A[byte >> 1] = f2b(a * inv);
    }
    {
      int g = g0 + n;
      int gc = (g < N) ? g : (N - 1);
      unsigned short xv = xb[((long)gc << 6) + lane];
      unsigned byte = (rbase + ((unsigned)(448 + lane) << 1)) ^ sw;
      A[byte >> 1] = xv;
    }
  }

  __syncthreads();

  // ---- phase 2: MFMA on own 16 rows ----
  const int row16 = lane & 15;
  const int kg = lane >> 4;
  const int lrow = (wv << 4) + row16;
  const unsigned sw2 = ((unsigned)(lrow & 7)) << 4;

  floatx4 c0 = {0,0,0,0}, c1 = {0,0,0,0}, c2 = {0,0,0,0}, c3 = {0,0,0,0};
  const short8* Bv = reinterpret_cast<const short8*>(Blg);

#pragma unroll
  for (int kk = 0; kk < 16; ++kk) {
    unsigned byte = ((((unsigned)lrow) << 10) +
                     ((unsigned)((kk << 5) + (kg << 3)) << 1)) ^ sw2;
    short8 aa = *reinterpret_cast<const short8*>(&A[byte >> 1]);
    const int bb = (kk * 4 + kg) * 64 + row16;
    c0 = __builtin_amdgcn_mfma_f32_16x16x32_bf16(aa, Bv[bb],      c0, 0, 0, 0);
    c1 = __builtin_amdgcn_mfma_f32_16x16x32_bf16(aa, Bv[bb + 16], c1, 0, 0, 0);
    c2 = __builtin_amdgcn_mfma_f32_16x16x32_bf16(aa, Bv[bb + 32], c2, 0, 0, 0);
    c3 = __builtin_amdgcn_mfma_f32_16x16x32_bf16(aa, Bv[bb + 48], c3, 0, 0, 0);
  }

  const int rowbase = blockIdx.x * 64 + (wv << 4);
  const int rowoff = kg * 4;
#pragma unroll
  for (int t = 0; t < 4; ++t) {
    floatx4 c = (t == 0) ? c0 : (t == 1) ? c1 : (t == 2) ? c2 : c3;
    const int col = t * 16 + row16;
    const float b = bias[col];
#pragma unroll
    for (int q = 0; q < 4; ++q) {
      int row = rowbase + rowoff + q;
      if (row < N) out[(long)row * DIM + col] = c[q] + b;
    }
  }
}

extern "C" void kernel_launch(void* const* d_in, const int* in_sizes, int n_in,
                              void* d_out, int out_size, void* d_ws, size_t ws_size,
                              hipStream_t stream)
{
  const float* x    = (const float*)d_in[0];
  const float* W    = (const float*)d_in[1];
  const float* root = (const float*)d_in[2];
  const float* bias = (const float*)d_in[3];
  const int*   ei   = (const int*)d_in[4];
  const int*   et   = (const int*)d_in[5];
  float* out = (float*)d_out;

  const int N = in_sizes[0] / DIM;
  const int E = in_sizes[4] / 2;
  const int NS = N * 8;  // segments = dst*8 + rel (r=7 bucket always empty)

  // workspace layout
  unsigned short* xb = (unsigned short*)d_ws;            // [N][64] bf16
  unsigned short* Blg = xb + (size_t)N * DIM;            // 64 KiB
  int* esrc   = (int*)(Blg + 4096 * 8);                  // [E]
  int* deg    = esrc + E;                                // [NS]
  int* start  = deg + NS;                                // [NS+1]
  int* cursor = start + NS + 1;                          // [NS]
  int* bsum   = cursor + NS;                             // [ceil(NS/1024)]

  hipMemsetAsync(deg, 0, (size_t)NS * sizeof(int), stream);
  k_xb<<<(int)(((long)N * DIM / 8 + 255) / 256), 256, 0, stream>>>(x, xb, (long)N * DIM / 8);
  k_wb<<<16, 256, 0, stream>>>(W, root, Blg);
  k_hist<<<(E + 255) / 256, 256, 0, stream>>>(ei + E, et, deg, E);
  int nb = (NS + 1023) / 1024;
  k_scan1<<<nb, 256, 0, stream>>>(deg, start, bsum, NS);
  k_scan2<<<1, 256, 0, stream>>>(bsum, nb);
  k_scan3<<<(NS + 1 + 255) / 256, 256, 0, stream>>>(start, cursor, bsum, NS, E);
  k_bucket<<<(E + 255) / 256, 256, 0, stream>>>(ei, et, cursor, esrc, E);
  k_fused<<<(N + 63) / 64, 256, 0, stream>>>(start, esrc, xb, Blg, bias, out, N, NS);
}

// Round 10
// 211.769 us; speedup vs baseline: 2.5126x; 2.5126x over previous
//
#include <hip/hip_runtime.h>
#include <hip/hip_bf16.h>

#define RELS 7
#define DIM 64

typedef __attribute__((ext_vector_type(8))) short short8;
typedef __attribute__((ext_vector_type(4))) float floatx4;

__device__ inline unsigned short f2b(float f) {
  union { float f; unsigned u; } v; v.f = f;
  unsigned u = v.u + 0x7fffu + ((v.u >> 16) & 1u);  // round-nearest-even
  return (unsigned short)(u >> 16);
}
__device__ inline float b2f(unsigned short b) {
  union { unsigned u; float f; } v; v.u = ((unsigned)b) << 16;
  return v.f;
}

// x f32 -> bf16 (8 elems/thread)
__global__ void __launch_bounds__(256) k_xb(const float* __restrict__ x,
                                            unsigned short* __restrict__ xb, long n8) {
  long t = (long)blockIdx.x * 256 + threadIdx.x;
  if (t >= n8) return;
  const float4* p = reinterpret_cast<const float4*>(x + t * 8);
  float4 f0 = p[0], f1 = p[1];
  short8 o;
  o[0] = (short)f2b(f0.x); o[1] = (short)f2b(f0.y);
  o[2] = (short)f2b(f0.z); o[3] = (short)f2b(f0.w);
  o[4] = (short)f2b(f1.x); o[5] = (short)f2b(f1.y);
  o[6] = (short)f2b(f1.z); o[7] = (short)f2b(f1.w);
  *reinterpret_cast<short8*>(xb + t * 8) = o;
}

// Wcat = [W_0..W_6 | root] as bf16 MFMA-B fragments: group g=(k>>3)*512+col
__global__ void __launch_bounds__(256) k_wcat(const float* __restrict__ W,
                                              const float* __restrict__ root,
                                              unsigned short* __restrict__ Bcat) {
  int g = blockIdx.x * 256 + threadIdx.x;  // 8 kb * 512 col = 4096
  if (g >= 4096) return;
  int kb = g >> 9, col = g & 511;
  int r = col >> 6, o = col & 63;
  short8 tmp;
#pragma unroll
  for (int j = 0; j < 8; ++j) {
    int k = kb * 8 + j;
    float v = (r < RELS) ? W[(r << 12) + (k << 6) + o] : root[(k << 6) + o];
    tmp[j] = (short)f2b(v);
  }
  *reinterpret_cast<short8*>(&Bcat[g * 8]) = tmp;
}

// xw[(i<<3)|r][o] = (xb[i] @ Wcat)[r*64+o]   M=100k K=64 N=512 bf16 GEMM
#define XW_TILE(T)                                                          \
  {                                                                         \
    const int col = (wv << 7) + (T << 4) + row16;                           \
    acc = {0, 0, 0, 0};                                                     \
    acc = __builtin_amdgcn_mfma_f32_16x16x32_bf16(a0, Bv[(kg << 9) + col], acc, 0, 0, 0);          \
    acc = __builtin_amdgcn_mfma_f32_16x16x32_bf16(a1, Bv[((4 + kg) << 9) + col], acc, 0, 0, 0);    \
    const int r = col >> 6, o = col & 63;                                   \
    _Pragma("unroll")                                                       \
    for (int q = 0; q < 4; ++q) {                                           \
      int n2 = i0 + (kg << 2) + q;                                          \
      if (n2 < N) xw[(((long)((n2 << 3) | r)) << 6) + o] = f2b(acc[q]);     \
    }                                                                       \
  }

__global__ void __launch_bounds__(256) k_xw(const unsigned short* __restrict__ xb,
                                            const unsigned short* __restrict__ Bcat,
                                            unsigned short* __restrict__ xw, int N) {
  const int tid = threadIdx.x;
  const int lane = tid & 63;
  const int wv = tid >> 6;          // wave -> col block of 128
  const int row16 = lane & 15;
  const int kg = lane >> 4;
  const int i0 = blockIdx.x * 16;
  int i = i0 + row16; if (i > N - 1) i = N - 1;

  short8 a0 = *reinterpret_cast<const short8*>(xb + ((long)i << 6) + (kg << 3));
  short8 a1 = *reinterpret_cast<const short8*>(xb + ((long)i << 6) + 32 + (kg << 3));
  const short8* Bv = reinterpret_cast<const short8*>(Bcat);
  floatx4 acc;
  XW_TILE(0) XW_TILE(1) XW_TILE(2) XW_TILE(3)
  XW_TILE(4) XW_TILE(5) XW_TILE(6) XW_TILE(7)
}

// histogram over (dst*8 + rel)  (real edges only)
__global__ void __launch_bounds__(256) k_hist(const int* __restrict__ dst,
                                              const int* __restrict__ et,
                                              int* __restrict__ deg, int E) {
  int e = blockIdx.x * 256 + threadIdx.x;
  if (e < E) atomicAdd(&deg[(dst[e] << 3) + et[e]], 1);
}

// per-node padded degree: roundup8(sum_r deg + 1 self)
__global__ void __launch_bounds__(256) k_dpad(const int* __restrict__ deg,
                                              int* __restrict__ darr, int N) {
  int i = blockIdx.x * 256 + threadIdx.x;
  if (i >= N) return;
  int s = 1;
#pragma unroll
  for (int r = 0; r < RELS; ++r) s += deg[(i << 3) + r];
  darr[i] = (s + 7) & ~7;
}

// block-local exclusive scan over 1024 entries (256 thr x 4)
__global__ void __launch_bounds__(256) k_scan1(const int* __restrict__ deg,
                                               int* __restrict__ start,
                                               int* __restrict__ bsum, int n) {
  __shared__ int sm[256];
  int t = threadIdx.x;
  int base = blockIdx.x * 1024 + t * 4;
  int v0 = (base + 0 < n) ? deg[base + 0] : 0;
  int v1 = (base + 1 < n) ? deg[base + 1] : 0;
  int v2 = (base + 2 < n) ? deg[base + 2] : 0;
  int v3 = (base + 3 < n) ? deg[base + 3] : 0;
  int s = v0 + v1 + v2 + v3;
  sm[t] = s;
  __syncthreads();
  for (int off = 1; off < 256; off <<= 1) {
    int a = (t >= off) ? sm[t - off] : 0;
    __syncthreads();
    sm[t] += a;
    __syncthreads();
  }
  int excl = sm[t] - s;
  if (base + 0 < n) start[base + 0] = excl;
  excl += v0;
  if (base + 1 < n) start[base + 1] = excl;
  excl += v1;
  if (base + 2 < n) start[base + 2] = excl;
  excl += v2;
  if (base + 3 < n) start[base + 3] = excl;
  if (t == 255) bsum[blockIdx.x] = sm[255];
}

// single-block exclusive scan over up to 1024 block sums (in place)
__global__ void __launch_bounds__(256) k_scan2(int* bsum, int nb) {
  __shared__ int sm[256];
  int t = threadIdx.x;
  int base = t * 4;
  int v0 = (base + 0 < nb) ? bsum[base + 0] : 0;
  int v1 = (base + 1 < nb) ? bsum[base + 1] : 0;
  int v2 = (base + 2 < nb) ? bsum[base + 2] : 0;
  int v3 = (base + 3 < nb) ? bsum[base + 3] : 0;
  int s = v0 + v1 + v2 + v3;
  sm[t] = s;
  __syncthreads();
  for (int off = 1; off < 256; off <<= 1) {
    int a = (t >= off) ? sm[t - off] : 0;
    __syncthreads();
    sm[t] += a;
    __syncthreads();
  }
  int excl = sm[t] - s;
  if (base + 0 < nb) bsum[base + 0] = excl;
  excl += v0;
  if (base + 1 < nb) bsum[base + 1] = excl;
  excl += v1;
  if (base + 2 < nb) bsum[base + 2] = excl;
  excl += v2;
  if (base + 3 < nb) bsum[base + 3] = excl;
}

// add block offsets; also produce total at nst[n]
__global__ void __launch_bounds__(256) k_scan3b(int* __restrict__ nst,
                                                const int* __restrict__ bsum,
                                                const int* __restrict__ darr, int n) {
  int i = blockIdx.x * 256 + threadIdx.x;
  if (i >= n) return;
  int v = nst[i] + bsum[i >> 10];
  nst[i] = v;
  if (i == n - 1) nst[n] = v + darr[i];
}

// per node: set per-seg cursors, fill w for real slots, self slot, w=0 pads
__global__ void __launch_bounds__(256) k_prep(const int* __restrict__ deg,
                                              const int* __restrict__ nst,
                                              int* __restrict__ cursor,
                                              int* __restrict__ esrc,
                                              float* __restrict__ w, int N) {
  int i = blockIdx.x * 256 + threadIdx.x;
  if (i >= N) return;
  int base = nst[i];
  int dend = nst[i + 1];
#pragma unroll
  for (int r = 0; r < RELS; ++r) {
    int seg = (i << 3) + r;
    int c = deg[seg];
    cursor[seg] = base;
    if (c) {
      float inv = __builtin_amdgcn_rcpf((float)c);
      for (int k = 0; k < c; ++k) w[base + k] = inv;
      base += c;
    }
  }
  esrc[base] = (i << 3) | 7;  // self edge -> root row
  w[base] = 1.0f;
  ++base;
  for (; base < dend; ++base) { esrc[base] = 0; w[base] = 0.0f; }
}

__global__ void __launch_bounds__(256) k_bucket(const int* __restrict__ ei,
                                                const int* __restrict__ et,
                                                int* __restrict__ cursor,
                                                int* __restrict__ esrc, int E) {
  int e = blockIdx.x * 256 + threadIdx.x;
  if (e >= E) return;
  int s = ei[e], d = ei[E + e], r = et[e];
  int pos = atomicAdd(&cursor[(d << 3) + r], 1);
  esrc[pos] = (s << 3) | r;  // xw row index
}

// one wave per node: out[nd] = sum_e w_e * xw[word_e] + bias
// branch-free (padded to x8, w=0 sentinels), no shfl, no routing.
__global__ void __launch_bounds__(256) k_gather(const int* __restrict__ nst,
                                                const int* __restrict__ esrc,
                                                const float* __restrict__ w,
                                                const unsigned short* __restrict__ xw,
                                                const float* __restrict__ bias,
                                                float* __restrict__ out, int N) {
  int nd = (int)(((long)blockIdx.x * 256 + threadIdx.x) >> 6);
  const int lane = threadIdx.x & 63;
  if (nd >= N) return;
  nd = __builtin_amdgcn_readfirstlane(nd);
  const int s    = __builtin_amdgcn_readfirstlane(nst[nd]);
  const int send = __builtin_amdgcn_readfirstlane(nst[nd + 1]);

  float a0 = 0, a1 = 0, a2 = 0, a3 = 0;
  const unsigned short* xwl = xw + lane;

  for (int e = s; e < send; e += 8) {
    int4 ia = *reinterpret_cast<const int4*>(esrc + e);
    int4 ib = *reinterpret_cast<const int4*>(esrc + e + 4);
    float4 wa = *reinterpret_cast<const float4*>(w + e);
    float4 wb = *reinterpret_cast<const float4*>(w + e + 4);
    float g0 = b2f(xwl[((long)ia.x) << 6]);
    float g1 = b2f(xwl[((long)ia.y) << 6]);
    float g2 = b2f(xwl[((long)ia.z) << 6]);
    float g3 = b2f(xwl[((long)ia.w) << 6]);
    float g4 = b2f(xwl[((long)ib.x) << 6]);
    float g5 = b2f(xwl[((long)ib.y) << 6]);
    float g6 = b2f(xwl[((long)ib.z) << 6]);
    float g7 = b2f(xwl[((long)ib.w) << 6]);
    a0 += wa.x * g0; a1 += wa.y * g1; a2 += wa.z * g2; a3 += wa.w * g3;
    a0 += wb.x * g4; a1 += wb.y * g5; a2 += wb.z * g6; a3 += wb.w * g7;
  }

  float r = (a0 + a1) + (a2 + a3) + bias[lane];
  out[((long)nd << 6) + lane] = r;
}

extern "C" void kernel_launch(void* const* d_in, const int* in_sizes, int n_in,
                              void* d_out, int out_size, void* d_ws, size_t ws_size,
                              hipStream_t stream)
{
  const float* x    = (const float*)d_in[0];
  const float* W    = (const float*)d_in[1];
  const float* root = (const float*)d_in[2];
  const float* bias = (const float*)d_in[3];
  const int*   ei   = (const int*)d_in[4];
  const int*   et   = (const int*)d_in[5];
  float* out = (float*)d_out;

  const int N = in_sizes[0] / DIM;
  const int E = in_sizes[4] / 2;
  const int NS = N * 8;

  // workspace layout
  unsigned short* xw  = (unsigned short*)d_ws;            // [N*8][64] bf16 = 102.4 MB
  unsigned short* xb  = xw + (size_t)NS * DIM;            // [N][64] bf16
  unsigned short* Bcat = xb + (size_t)N * DIM;            // 64 KiB
  int*   esrc  = (int*)(Bcat + 4096 * 8);                 // [E + 8N]
  float* wgt   = (float*)(esrc + E + 8 * N);              // [E + 8N]
  int*   deg   = (int*)(wgt + E + 8 * N);                 // [NS]
  int*   darr  = deg + NS;                                // [N]
  int*   nst   = darr + N;                                // [N+1]
  int*   cursor = nst + N + 1;                            // [NS]
  int*   bsum  = cursor + NS;                             // [ceil(N/1024)]

  hipMemsetAsync(deg, 0, (size_t)NS * sizeof(int), stream);
  k_xb<<<(int)(((long)N * DIM / 8 + 255) / 256), 256, 0, stream>>>(x, xb, (long)N * DIM / 8);
  k_wcat<<<16, 256, 0, stream>>>(W, root, Bcat);
  k_xw<<<(N + 15) / 16, 256, 0, stream>>>(xb, Bcat, xw, N);
  k_hist<<<(E + 255) / 256, 256, 0, stream>>>(ei + E, et, deg, E);
  k_dpad<<<(N + 255) / 256, 256, 0, stream>>>(deg, darr, N);
  int nb = (N + 1023) / 1024;
  k_scan1<<<nb, 256, 0, stream>>>(darr, nst, bsum, N);
  k_scan2<<<1, 256, 0, stream>>>(bsum, nb);
  k_scan3b<<<(N + 255) / 256, 256, 0, stream>>>(nst, bsum, darr, N);
  k_prep<<<(N + 255) / 256, 256, 0, stream>>>(deg, nst, cursor, esrc, wgt, N);
  k_bucket<<<(E + 255) / 256, 256, 0, stream>>>(ei, et, cursor, esrc, E);
  k_gather<<<(N + 3) / 4, 256, 0, stream>>>(nst, esrc, wgt, xw, bias, out, N);
}

// Round 11
// 185.212 us; speedup vs baseline: 2.8729x; 1.1434x over previous
//
#include <hip/hip_runtime.h>
#include <hip/hip_bf16.h>

#define RELS 7
#define DIM 64

typedef __attribute__((ext_vector_type(8))) short short8;
typedef __attribute__((ext_vector_type(4))) float floatx4;

__device__ inline unsigned short f2b(float f) {
  union { float f; unsigned u; } v; v.f = f;
  unsigned u = v.u + 0x7fffu + ((v.u >> 16) & 1u);  // round-nearest-even
  return (unsigned short)(u >> 16);
}
__device__ inline float b2f(unsigned short b) {
  union { unsigned u; float f; } v; v.u = ((unsigned)b) << 16;
  return v.f;
}

// x f32 -> bf16 (8 elems/thread)
__global__ void __launch_bounds__(256) k_xb(const float* __restrict__ x,
                                            unsigned short* __restrict__ xb, long n8) {
  long t = (long)blockIdx.x * 256 + threadIdx.x;
  if (t >= n8) return;
  const float4* p = reinterpret_cast<const float4*>(x + t * 8);
  float4 f0 = p[0], f1 = p[1];
  short8 o;
  o[0] = (short)f2b(f0.x); o[1] = (short)f2b(f0.y);
  o[2] = (short)f2b(f0.z); o[3] = (short)f2b(f0.w);
  o[4] = (short)f2b(f1.x); o[5] = (short)f2b(f1.y);
  o[6] = (short)f2b(f1.z); o[7] = (short)f2b(f1.w);
  *reinterpret_cast<short8*>(xb + t * 8) = o;
}

// Wcat = [W_0..W_6 | root] as bf16 MFMA-B fragments: group g=(k>>3)*512+col
__global__ void __launch_bounds__(256) k_wcat(const float* __restrict__ W,
                                              const float* __restrict__ root,
                                              unsigned short* __restrict__ Bcat) {
  int g = blockIdx.x * 256 + threadIdx.x;  // 8 kb * 512 col = 4096
  if (g >= 4096) return;
  int kb = g >> 9, col = g & 511;
  int r = col >> 6, o = col & 63;
  short8 tmp;
#pragma unroll
  for (int j = 0; j < 8; ++j) {
    int k = kb * 8 + j;
    float v = (r < RELS) ? W[(r << 12) + (k << 6) + o] : root[(k << 6) + o];
    tmp[j] = (short)f2b(v);
  }
  *reinterpret_cast<short8*>(&Bcat[g * 8]) = tmp;
}

// xw[(i<<3)|r][o] = (xb[i] @ Wcat)[r*64+o]   M=100k K=64 N=512 bf16 GEMM
#define XW_TILE(T)                                                          \
  {                                                                         \
    const int col = (wv << 7) + (T << 4) + row16;                           \
    acc = {0, 0, 0, 0};                                                     \
    acc = __builtin_amdgcn_mfma_f32_16x16x32_bf16(a0, Bv[(kg << 9) + col], acc, 0, 0, 0);          \
    acc = __builtin_amdgcn_mfma_f32_16x16x32_bf16(a1, Bv[((4 + kg) << 9) + col], acc, 0, 0, 0);    \
    const int r = col >> 6, o = col & 63;                                   \
    _Pragma("unroll")                                                       \
    for (int q = 0; q < 4; ++q) {                                           \
      int n2 = i0 + (kg << 2) + q;                                          \
      if (n2 < N) xw[(((long)((n2 << 3) | r)) << 6) + o] = f2b(acc[q]);     \
    }                                                                       \
  }

__global__ void __launch_bounds__(256) k_xw(const unsigned short* __restrict__ xb,
                                            const unsigned short* __restrict__ Bcat,
                                            unsigned short* __restrict__ xw, int N) {
  const int tid = threadIdx.x;
  const int lane = tid & 63;
  const int wv = tid >> 6;          // wave -> col block of 128
  const int row16 = lane & 15;
  const int kg = lane >> 4;
  const int i0 = blockIdx.x * 16;
  int i = i0 + row16; if (i > N - 1) i = N - 1;

  short8 a0 = *reinterpret_cast<const short8*>(xb + ((long)i << 6) + (kg << 3));
  short8 a1 = *reinterpret_cast<const short8*>(xb + ((long)i << 6) + 32 + (kg << 3));
  const short8* Bv = reinterpret_cast<const short8*>(Bcat);
  floatx4 acc;
  XW_TILE(0) XW_TILE(1) XW_TILE(2) XW_TILE(3)
  XW_TILE(4) XW_TILE(5) XW_TILE(6) XW_TILE(7)
}

// XCD-partitioned histogram over (dst*8 + rel): partition p = bid&7 owns
// dst range [p*Np, (p+1)*Np) -> deg lines only touched by one XCD.
__global__ void __launch_bounds__(256) k_hist(const int* __restrict__ dst,
                                              const int* __restrict__ et,
                                              int* __restrict__ deg, int E, int N) {
  int p = blockIdx.x & 7;
  int e = (blockIdx.x >> 3) * 256 + threadIdx.x;
  if (e >= E) return;
  int Np = (N + 7) >> 3;
  int d = dst[e];
  if (d < p * Np || d >= (p + 1) * Np) return;
  atomicAdd(&deg[(d << 3) + et[e]], 1);
}

// per-node padded degree: roundup8(sum_r deg + 1 self)
__global__ void __launch_bounds__(256) k_dpad(const int* __restrict__ deg,
                                              int* __restrict__ darr, int N) {
  int i = blockIdx.x * 256 + threadIdx.x;
  if (i >= N) return;
  int s = 1;
#pragma unroll
  for (int r = 0; r < RELS; ++r) s += deg[(i << 3) + r];
  darr[i] = (s + 7) & ~7;
}

// block-local exclusive scan over 1024 entries (256 thr x 4)
__global__ void __launch_bounds__(256) k_scan1(const int* __restrict__ deg,
                                               int* __restrict__ start,
                                               int* __restrict__ bsum, int n) {
  __shared__ int sm[256];
  int t = threadIdx.x;
  int base = blockIdx.x * 1024 + t * 4;
  int v0 = (base + 0 < n) ? deg[base + 0] : 0;
  int v1 = (base + 1 < n) ? deg[base + 1] : 0;
  int v2 = (base + 2 < n) ? deg[base + 2] : 0;
  int v3 = (base + 3 < n) ? deg[base + 3] : 0;
  int s = v0 + v1 + v2 + v3;
  sm[t] = s;
  __syncthreads();
  for (int off = 1; off < 256; off <<= 1) {
    int a = (t >= off) ? sm[t - off] : 0;
    __syncthreads();
    sm[t] += a;
    __syncthreads();
  }
  int excl = sm[t] - s;
  if (base + 0 < n) start[base + 0] = excl;
  excl += v0;
  if (base + 1 < n) start[base + 1] = excl;
  excl += v1;
  if (base + 2 < n) start[base + 2] = excl;
  excl += v2;
  if (base + 3 < n) start[base + 3] = excl;
  if (t == 255) bsum[blockIdx.x] = sm[255];
}

// single-block exclusive scan over up to 1024 block sums (in place)
__global__ void __launch_bounds__(256) k_scan2(int* bsum, int nb) {
  __shared__ int sm[256];
  int t = threadIdx.x;
  int base = t * 4;
  int v0 = (base + 0 < nb) ? bsum[base + 0] : 0;
  int v1 = (base + 1 < nb) ? bsum[base + 1] : 0;
  int v2 = (base + 2 < nb) ? bsum[base + 2] : 0;
  int v3 = (base + 3 < nb) ? bsum[base + 3] : 0;
  int s = v0 + v1 + v2 + v3;
  sm[t] = s;
  __syncthreads();
  for (int off = 1; off < 256; off <<= 1) {
    int a = (t >= off) ? sm[t - off] : 0;
    __syncthreads();
    sm[t] += a;
    __syncthreads();
  }
  int excl = sm[t] - s;
  if (base + 0 < nb) bsum[base + 0] = excl;
  excl += v0;
  if (base + 1 < nb) bsum[base + 1] = excl;
  excl += v1;
  if (base + 2 < nb) bsum[base + 2] = excl;
  excl += v2;
  if (base + 3 < nb) bsum[base + 3] = excl;
}

// add block offsets; also produce total at nst[n]
__global__ void __launch_bounds__(256) k_scan3b(int* __restrict__ nst,
                                                const int* __restrict__ bsum,
                                                const int* __restrict__ darr, int n) {
  int i = blockIdx.x * 256 + threadIdx.x;
  if (i >= n) return;
  int v = nst[i] + bsum[i >> 10];
  nst[i] = v;
  if (i == n - 1) nst[n] = v + darr[i];
}

// per node: per-seg cursors, self slot (c=1), zero pads (c=0)
__global__ void __launch_bounds__(256) k_prep(const int* __restrict__ deg,
                                              const int* __restrict__ nst,
                                              int* __restrict__ cursor,
                                              int* __restrict__ esrc, int N) {
  int i = blockIdx.x * 256 + threadIdx.x;
  if (i >= N) return;
  int base = nst[i];
  int dend = nst[i + 1];
#pragma unroll
  for (int r = 0; r < RELS; ++r) {
    int seg = (i << 3) + r;
    cursor[seg] = base;
    base += deg[seg];
  }
  esrc[base] = ((i << 3) | 7) | (1 << 20);  // self edge -> root row, c=1
  ++base;
  for (; base < dend; ++base) esrc[base] = 0;  // pad: row 0, c=0 -> w=0
}

// XCD-partitioned scatter: partition p = bid&7 owns dst range -> esrc/cursor
// lines written by a single XCD (no cross-XCD line bouncing / write-amp).
// word = row(20) | min(c,4095)<<20
__global__ void __launch_bounds__(256) k_bucket(const int* __restrict__ ei,
                                                const int* __restrict__ et,
                                                const int* __restrict__ deg,
                                                int* __restrict__ cursor,
                                                int* __restrict__ esrc, int E, int N) {
  int p = blockIdx.x & 7;
  int e = (blockIdx.x >> 3) * 256 + threadIdx.x;
  if (e >= E) return;
  int Np = (N + 7) >> 3;
  int d = ei[E + e];
  if (d < p * Np || d >= (p + 1) * Np) return;
  int s = ei[e], r = et[e];
  int seg = (d << 3) + r;
  int pos = atomicAdd(&cursor[seg], 1);
  int c = deg[seg]; if (c > 4095) c = 4095;
  esrc[pos] = (s << 3) | r | (c << 20);
}

// one wave per node: out[nd] = sum_e w_e * xw[row_e] + bias
// w derived in-register from packed count; branch-free, padded to x8.
__global__ void __launch_bounds__(256) k_gather(const int* __restrict__ nst,
                                                const int* __restrict__ esrc,
                                                const unsigned short* __restrict__ xw,
                                                const float* __restrict__ bias,
                                                float* __restrict__ out, int N) {
  int nd = (int)(((long)blockIdx.x * 256 + threadIdx.x) >> 6);
  const int lane = threadIdx.x & 63;
  if (nd >= N) return;
  nd = __builtin_amdgcn_readfirstlane(nd);
  const int s    = __builtin_amdgcn_readfirstlane(nst[nd]);
  const int send = __builtin_amdgcn_readfirstlane(nst[nd + 1]);

  float a0 = 0, a1 = 0, a2 = 0, a3 = 0;
  const unsigned short* xwl = xw + lane;

  for (int e = s; e < send; e += 8) {
    int4 ia = *reinterpret_cast<const int4*>(esrc + e);
    int4 ib = *reinterpret_cast<const int4*>(esrc + e + 4);
    float g0 = b2f(xwl[((long)(ia.x & 0xFFFFF)) << 6]);
    float g1 = b2f(xwl[((long)(ia.y & 0xFFFFF)) << 6]);
    float g2 = b2f(xwl[((long)(ia.z & 0xFFFFF)) << 6]);
    float g3 = b2f(xwl[((long)(ia.w & 0xFFFFF)) << 6]);
    float g4 = b2f(xwl[((long)(ib.x & 0xFFFFF)) << 6]);
    float g5 = b2f(xwl[((long)(ib.y & 0xFFFFF)) << 6]);
    float g6 = b2f(xwl[((long)(ib.z & 0xFFFFF)) << 6]);
    float g7 = b2f(xwl[((long)(ib.w & 0xFFFFF)) << 6]);
    unsigned c0 = ((unsigned)ia.x) >> 20, c1 = ((unsigned)ia.y) >> 20;
    unsigned c2 = ((unsigned)ia.z) >> 20, c3 = ((unsigned)ia.w) >> 20;
    unsigned c4 = ((unsigned)ib.x) >> 20, c5 = ((unsigned)ib.y) >> 20;
    unsigned c6 = ((unsigned)ib.z) >> 20, c7 = ((unsigned)ib.w) >> 20;
    float w0 = c0 ? __builtin_amdgcn_rcpf((float)c0) : 0.0f;
    float w1 = c1 ? __builtin_amdgcn_rcpf((float)c1) : 0.0f;
    float w2 = c2 ? __builtin_amdgcn_rcpf((float)c2) : 0.0f;
    float w3 = c3 ? __builtin_amdgcn_rcpf((float)c3) : 0.0f;
    float w4 = c4 ? __builtin_amdgcn_rcpf((float)c4) : 0.0f;
    float w5 = c5 ? __builtin_amdgcn_rcpf((float)c5) : 0.0f;
    float w6 = c6 ? __builtin_amdgcn_rcpf((float)c6) : 0.0f;
    float w7 = c7 ? __builtin_amdgcn_rcpf((float)c7) : 0.0f;
    a0 += w0 * g0; a1 += w1 * g1; a2 += w2 * g2; a3 += w3 * g3;
    a0 += w4 * g4; a1 += w5 * g5; a2 += w6 * g6; a3 += w7 * g7;
  }

  float r = (a0 + a1) + (a2 + a3) + bias[lane];
  out[((long)nd << 6) + lane] = r;
}

extern "C" void kernel_launch(void* const* d_in, const int* in_sizes, int n_in,
                              void* d_out, int out_size, void* d_ws, size_t ws_size,
                              hipStream_t stream)
{
  const float* x    = (const float*)d_in[0];
  const float* W    = (const float*)d_in[1];
  const float* root = (const float*)d_in[2];
  const float* bias = (const float*)d_in[3];
  const int*   ei   = (const int*)d_in[4];
  const int*   et   = (const int*)d_in[5];
  float* out = (float*)d_out;

  const int N = in_sizes[0] / DIM;
  const int E = in_sizes[4] / 2;
  const int NS = N * 8;

  // workspace layout
  unsigned short* xw  = (unsigned short*)d_ws;            // [N*8][64] bf16 = 102.4 MB
  unsigned short* xb  = xw + (size_t)NS * DIM;            // [N][64] bf16
  unsigned short* Bcat = xb + (size_t)N * DIM;            // 64 KiB
  int*   esrc  = (int*)(Bcat + 4096 * 8);                 // [E + 8N]
  int*   deg   = esrc + E + 8 * N;                        // [NS]
  int*   darr  = deg + NS;                                // [N]
  int*   nst   = darr + N;                                // [N+1]
  int*   cursor = nst + N + 1;                            // [NS]
  int*   bsum  = cursor + NS;                             // [ceil(N/1024)]

  hipMemsetAsync(deg, 0, (size_t)NS * sizeof(int), stream);
  k_xb<<<(int)(((long)N * DIM / 8 + 255) / 256), 256, 0, stream>>>(x, xb, (long)N * DIM / 8);
  k_wcat<<<16, 256, 0, stream>>>(W, root, Bcat);
  k_xw<<<(N + 15) / 16, 256, 0, stream>>>(xb, Bcat, xw, N);
  int bpp = (E + 255) / 256;  // blocks per XCD partition
  k_hist<<<bpp * 8, 256, 0, stream>>>(ei + E, et, deg, E, N);
  k_dpad<<<(N + 255) / 256, 256, 0, stream>>>(deg, darr, N);
  int nb = (N + 1023) / 1024;
  k_scan1<<<nb, 256, 0, stream>>>(darr, nst, bsum, N);
  k_scan2<<<1, 256, 0, stream>>>(bsum, nb);
  k_scan3b<<<(N + 255) / 256, 256, 0, stream>>>(nst, bsum, darr, N);
  k_prep<<<(N + 255) / 256, 256, 0, stream>>>(deg, nst, cursor, esrc, N);
  k_bucket<<<bpp * 8, 256, 0, stream>>>(ei, et, deg, cursor, esrc, E, N);
  k_gather<<<(N + 3) / 4, 256, 0, stream>>>(nst, esrc, xw, bias, out, N);
}

// Round 12
// 165.140 us; speedup vs baseline: 3.2221x; 1.1215x over previous
//
#include <hip/hip_runtime.h>
#include <hip/hip_bf16.h>

#define RELS 7
#define DIM 64

typedef __attribute__((ext_vector_type(8))) short short8;
typedef __attribute__((ext_vector_type(4))) float floatx4;

__device__ inline unsigned short f2b(float f) {
  union { float f; unsigned u; } v; v.f = f;
  unsigned u = v.u + 0x7fffu + ((v.u >> 16) & 1u);  // round-nearest-even
  return (unsigned short)(u >> 16);
}
__device__ inline float b2f(unsigned short b) {
  union { unsigned u; float f; } v; v.u = ((unsigned)b) << 16;
  return v.f;
}

// x f32 -> bf16 (8 elems/thread)
__global__ void __launch_bounds__(256) k_xb(const float* __restrict__ x,
                                            unsigned short* __restrict__ xb, long n8) {
  long t = (long)blockIdx.x * 256 + threadIdx.x;
  if (t >= n8) return;
  const float4* p = reinterpret_cast<const float4*>(x + t * 8);
  float4 f0 = p[0], f1 = p[1];
  short8 o;
  o[0] = (short)f2b(f0.x); o[1] = (short)f2b(f0.y);
  o[2] = (short)f2b(f0.z); o[3] = (short)f2b(f0.w);
  o[4] = (short)f2b(f1.x); o[5] = (short)f2b(f1.y);
  o[6] = (short)f2b(f1.z); o[7] = (short)f2b(f1.w);
  *reinterpret_cast<short8*>(xb + t * 8) = o;
}

// Wcat = [W_0..W_6 | root] as bf16 MFMA-B fragments: group g=(k>>3)*512+col
__global__ void __launch_bounds__(256) k_wcat(const float* __restrict__ W,
                                              const float* __restrict__ root,
                                              unsigned short* __restrict__ Bcat) {
  int g = blockIdx.x * 256 + threadIdx.x;  // 8 kb * 512 col = 4096
  if (g >= 4096) return;
  int kb = g >> 9, col = g & 511;
  int r = col >> 6, o = col & 63;
  short8 tmp;
#pragma unroll
  for (int j = 0; j < 8; ++j) {
    int k = kb * 8 + j;
    float v = (r < RELS) ? W[(r << 12) + (k << 6) + o] : root[(k << 6) + o];
    tmp[j] = (short)f2b(v);
  }
  *reinterpret_cast<short8*>(&Bcat[g * 8]) = tmp;
}

// xw[(i<<3)|r][o] = (xb[i] @ Wcat)[r*64+o]   M=100k K=64 N=512 bf16 GEMM
#define XW_TILE(T)                                                          \
  {                                                                         \
    const int col = (wv << 7) + (T << 4) + row16;                           \
    acc = {0, 0, 0, 0};                                                     \
    acc = __builtin_amdgcn_mfma_f32_16x16x32_bf16(a0, Bv[(kg << 9) + col], acc, 0, 0, 0);          \
    acc = __builtin_amdgcn_mfma_f32_16x16x32_bf16(a1, Bv[((4 + kg) << 9) + col], acc, 0, 0, 0);    \
    const int r = col >> 6, o = col & 63;                                   \
    _Pragma("unroll")                                                       \
    for (int q = 0; q < 4; ++q) {                                           \
      int n2 = i0 + (kg << 2) + q;                                          \
      if (n2 < N) xw[(((long)((n2 << 3) | r)) << 6) + o] = f2b(acc[q]);     \
    }                                                                       \
  }

__global__ void __launch_bounds__(256) k_xw(const unsigned short* __restrict__ xb,
                                            const unsigned short* __restrict__ Bcat,
                                            unsigned short* __restrict__ xw, int N) {
  const int tid = threadIdx.x;
  const int lane = tid & 63;
  const int wv = tid >> 6;          // wave -> col block of 128
  const int row16 = lane & 15;
  const int kg = lane >> 4;
  const int i0 = blockIdx.x * 16;
  int i = i0 + row16; if (i > N - 1) i = N - 1;

  short8 a0 = *reinterpret_cast<const short8*>(xb + ((long)i << 6) + (kg << 3));
  short8 a1 = *reinterpret_cast<const short8*>(xb + ((long)i << 6) + 32 + (kg << 3));
  const short8* Bv = reinterpret_cast<const short8*>(Bcat);
  floatx4 acc;
  XW_TILE(0) XW_TILE(1) XW_TILE(2) XW_TILE(3)
  XW_TILE(4) XW_TILE(5) XW_TILE(6) XW_TILE(7)
}

// ONE atomic pass: rank[e] = atomicAdd(deg[seg]); afterwards deg = counts.
__global__ void __launch_bounds__(256) k_rank(const int* __restrict__ dst,
                                              const int* __restrict__ et,
                                              int* __restrict__ deg,
                                              unsigned short* __restrict__ rank, int E) {
  int e = blockIdx.x * 256 + threadIdx.x;
  if (e >= E) return;
  int seg = (dst[e] << 3) + et[e];
  int r = atomicAdd(&deg[seg], 1);
  rank[e] = (unsigned short)(r > 65535 ? 65535 : r);
}

// per-node padded degree: roundup8(sum_r deg + 1 self)
__global__ void __launch_bounds__(256) k_dpad(const int* __restrict__ deg,
                                              int* __restrict__ darr, int N) {
  int i = blockIdx.x * 256 + threadIdx.x;
  if (i >= N) return;
  int s = 1;
#pragma unroll
  for (int r = 0; r < RELS; ++r) s += deg[(i << 3) + r];
  darr[i] = (s + 7) & ~7;
}

// block-local exclusive scan over 1024 entries (256 thr x 4)
__global__ void __launch_bounds__(256) k_scan1(const int* __restrict__ deg,
                                               int* __restrict__ start,
                                               int* __restrict__ bsum, int n) {
  __shared__ int sm[256];
  int t = threadIdx.x;
  int base = blockIdx.x * 1024 + t * 4;
  int v0 = (base + 0 < n) ? deg[base + 0] : 0;
  int v1 = (base + 1 < n) ? deg[base + 1] : 0;
  int v2 = (base + 2 < n) ? deg[base + 2] : 0;
  int v3 = (base + 3 < n) ? deg[base + 3] : 0;
  int s = v0 + v1 + v2 + v3;
  sm[t] = s;
  __syncthreads();
  for (int off = 1; off < 256; off <<= 1) {
    int a = (t >= off) ? sm[t - off] : 0;
    __syncthreads();
    sm[t] += a;
    __syncthreads();
  }
  int excl = sm[t] - s;
  if (base + 0 < n) start[base + 0] = excl;
  excl += v0;
  if (base + 1 < n) start[base + 1] = excl;
  excl += v1;
  if (base + 2 < n) start[base + 2] = excl;
  excl += v2;
  if (base + 3 < n) start[base + 3] = excl;
  if (t == 255) bsum[blockIdx.x] = sm[255];
}

// single-block exclusive scan over up to 1024 block sums (in place)
__global__ void __launch_bounds__(256) k_scan2(int* bsum, int nb) {
  __shared__ int sm[256];
  int t = threadIdx.x;
  int base = t * 4;
  int v0 = (base + 0 < nb) ? bsum[base + 0] : 0;
  int v1 = (base + 1 < nb) ? bsum[base + 1] : 0;
  int v2 = (base + 2 < nb) ? bsum[base + 2] : 0;
  int v3 = (base + 3 < nb) ? bsum[base + 3] : 0;
  int s = v0 + v1 + v2 + v3;
  sm[t] = s;
  __syncthreads();
  for (int off = 1; off < 256; off <<= 1) {
    int a = (t >= off) ? sm[t - off] : 0;
    __syncthreads();
    sm[t] += a;
    __syncthreads();
  }
  int excl = sm[t] - s;
  if (base + 0 < nb) bsum[base + 0] = excl;
  excl += v0;
  if (base + 1 < nb) bsum[base + 1] = excl;
  excl += v1;
  if (base + 2 < nb) bsum[base + 2] = excl;
  excl += v2;
  if (base + 3 < nb) bsum[base + 3] = excl;
}

// add block offsets; also produce total at nst[n]
__global__ void __launch_bounds__(256) k_scan3b(int* __restrict__ nst,
                                                const int* __restrict__ bsum,
                                                const int* __restrict__ darr, int n) {
  int i = blockIdx.x * 256 + threadIdx.x;
  if (i >= n) return;
  int v = nst[i] + bsum[i >> 10];
  nst[i] = v;
  if (i == n - 1) nst[n] = v + darr[i];
}

// per node: per-seg start offsets (cursor, read-only after), self slot, pads
__global__ void __launch_bounds__(256) k_prep(const int* __restrict__ deg,
                                              const int* __restrict__ nst,
                                              int* __restrict__ cursor,
                                              int* __restrict__ esrc, int N) {
  int i = blockIdx.x * 256 + threadIdx.x;
  if (i >= N) return;
  int base = nst[i];
  int dend = nst[i + 1];
#pragma unroll
  for (int r = 0; r < RELS; ++r) {
    int seg = (i << 3) + r;
    cursor[seg] = base;
    base += deg[seg];
  }
  esrc[base] = ((i << 3) | 7) | (1 << 20);  // self edge -> root row, c=1
  ++base;
  for (; base < dend; ++base) esrc[base] = 0;  // pad: row 0, c=0 -> w=0
}

// Atomic-free XCD-partitioned placement: pos = cursor[seg] + rank[e].
// word = row(20) | min(c,4095)<<20
__global__ void __launch_bounds__(256) k_place(const int* __restrict__ ei,
                                               const int* __restrict__ et,
                                               const int* __restrict__ deg,
                                               const int* __restrict__ cursor,
                                               const unsigned short* __restrict__ rank,
                                               int* __restrict__ esrc, int E, int N) {
  int p = blockIdx.x & 7;
  int e = (blockIdx.x >> 3) * 256 + threadIdx.x;
  if (e >= E) return;
  int Np = (N + 7) >> 3;
  int d = ei[E + e];
  if (d < p * Np || d >= (p + 1) * Np) return;
  int s = ei[e], r = et[e];
  int seg = (d << 3) + r;
  int pos = cursor[seg] + (int)rank[e];
  int c = deg[seg]; if (c > 4095) c = 4095;
  esrc[pos] = (s << 3) | r | (c << 20);
}

// one wave per node: out[nd] = sum_e w_e * xw[row_e] + bias
// w derived in-register from packed count; branch-free, padded to x8.
__global__ void __launch_bounds__(256) k_gather(const int* __restrict__ nst,
                                                const int* __restrict__ esrc,
                                                const unsigned short* __restrict__ xw,
                                                const float* __restrict__ bias,
                                                float* __restrict__ out, int N) {
  int nd = (int)(((long)blockIdx.x * 256 + threadIdx.x) >> 6);
  const int lane = threadIdx.x & 63;
  if (nd >= N) return;
  nd = __builtin_amdgcn_readfirstlane(nd);
  const int s    = __builtin_amdgcn_readfirstlane(nst[nd]);
  const int send = __builtin_amdgcn_readfirstlane(nst[nd + 1]);

  float a0 = 0, a1 = 0, a2 = 0, a3 = 0;
  const unsigned short* xwl = xw + lane;

  for (int e = s; e < send; e += 8) {
    int4 ia = *reinterpret_cast<const int4*>(esrc + e);
    int4 ib = *reinterpret_cast<const int4*>(esrc + e + 4);
    float g0 = b2f(xwl[((long)(ia.x & 0xFFFFF)) << 6]);
    float g1 = b2f(xwl[((long)(ia.y & 0xFFFFF)) << 6]);
    float g2 = b2f(xwl[((long)(ia.z & 0xFFFFF)) << 6]);
    float g3 = b2f(xwl[((long)(ia.w & 0xFFFFF)) << 6]);
    float g4 = b2f(xwl[((long)(ib.x & 0xFFFFF)) << 6]);
    float g5 = b2f(xwl[((long)(ib.y & 0xFFFFF)) << 6]);
    float g6 = b2f(xwl[((long)(ib.z & 0xFFFFF)) << 6]);
    float g7 = b2f(xwl[((long)(ib.w & 0xFFFFF)) << 6]);
    unsigned c0 = ((unsigned)ia.x) >> 20, c1 = ((unsigned)ia.y) >> 20;
    unsigned c2 = ((unsigned)ia.z) >> 20, c3 = ((unsigned)ia.w) >> 20;
    unsigned c4 = ((unsigned)ib.x) >> 20, c5 = ((unsigned)ib.y) >> 20;
    unsigned c6 = ((unsigned)ib.z) >> 20, c7 = ((unsigned)ib.w) >> 20;
    float w0 = c0 ? __builtin_amdgcn_rcpf((float)c0) : 0.0f;
    float w1 = c1 ? __builtin_amdgcn_rcpf((float)c1) : 0.0f;
    float w2 = c2 ? __builtin_amdgcn_rcpf((float)c2) : 0.0f;
    float w3 = c3 ? __builtin_amdgcn_rcpf((float)c3) : 0.0f;
    float w4 = c4 ? __builtin_amdgcn_rcpf((float)c4) : 0.0f;
    float w5 = c5 ? __builtin_amdgcn_rcpf((float)c5) : 0.0f;
    float w6 = c6 ? __builtin_amdgcn_rcpf((float)c6) : 0.0f;
    float w7 = c7 ? __builtin_amdgcn_rcpf((float)c7) : 0.0f;
    a0 += w0 * g0; a1 += w1 * g1; a2 += w2 * g2; a3 += w3 * g3;
    a0 += w4 * g4; a1 += w5 * g5; a2 += w6 * g6; a3 += w7 * g7;
  }

  float r = (a0 + a1) + (a2 + a3) + bias[lane];
  out[((long)nd << 6) + lane] = r;
}

extern "C" void kernel_launch(void* const* d_in, const int* in_sizes, int n_in,
                              void* d_out, int out_size, void* d_ws, size_t ws_size,
                              hipStream_t stream)
{
  const float* x    = (const float*)d_in[0];
  const float* W    = (const float*)d_in[1];
  const float* root = (const float*)d_in[2];
  const float* bias = (const float*)d_in[3];
  const int*   ei   = (const int*)d_in[4];
  const int*   et   = (const int*)d_in[5];
  float* out = (float*)d_out;

  const int N = in_sizes[0] / DIM;
  const int E = in_sizes[4] / 2;
  const int NS = N * 8;

  // workspace layout
  unsigned short* xw  = (unsigned short*)d_ws;            // [N*8][64] bf16 = 102.4 MB
  unsigned short* xb  = xw + (size_t)NS * DIM;            // [N][64] bf16
  unsigned short* Bcat = xb + (size_t)N * DIM;            // 64 KiB
  int*   esrc  = (int*)(Bcat + 4096 * 8);                 // [E + 8N]
  unsigned short* rank = (unsigned short*)(esrc + E + 8 * N);  // [E] (2 MB)
  int*   deg   = (int*)(rank + ((E + 1) & ~1));           // [NS]
  int*   darr  = deg + NS;                                // [N]
  int*   nst   = darr + N;                                // [N+1]
  int*   cursor = nst + N + 1;                            // [NS]
  int*   bsum  = cursor + NS;                             // [ceil(N/1024)]

  hipMemsetAsync(deg, 0, (size_t)NS * sizeof(int), stream);
  k_xb<<<(int)(((long)N * DIM / 8 + 255) / 256), 256, 0, stream>>>(x, xb, (long)N * DIM / 8);
  k_wcat<<<16, 256, 0, stream>>>(W, root, Bcat);
  k_xw<<<(N + 15) / 16, 256, 0, stream>>>(xb, Bcat, xw, N);
  k_rank<<<(E + 255) / 256, 256, 0, stream>>>(ei + E, et, deg, rank, E);
  k_dpad<<<(N + 255) / 256, 256, 0, stream>>>(deg, darr, N);
  int nb = (N + 1023) / 1024;
  k_scan1<<<nb, 256, 0, stream>>>(darr, nst, bsum, N);
  k_scan2<<<1, 256, 0, stream>>>(bsum, nb);
  k_scan3b<<<(N + 255) / 256, 256, 0, stream>>>(nst, bsum, darr, N);
  k_prep<<<(N + 255) / 256, 256, 0, stream>>>(deg, nst, cursor, esrc, N);
  int bpp = (E + 255) / 256;  // blocks per XCD partition
  k_place<<<bpp * 8, 256, 0, stream>>>(ei, et, deg, cursor, rank, esrc, E, N);
  k_gather<<<(N + 3) / 4, 256, 0, stream>>>(nst, esrc, xw, bias, out, N);
}